// Round 7
// baseline (440.427 us; speedup 1.0000x reference)
//
#include <hip/hip_runtime.h>
#include <math.h>

#define B_ 64
#define L_ 1024
#define D_ 64

typedef float4 f4;
typedef __attribute__((ext_vector_type(8))) short bf16x8;
typedef __attribute__((ext_vector_type(4))) float f32x4;

#define MFMA16(a, b, c) __builtin_amdgcn_mfma_f32_16x16x32_bf16(a, b, c, 0, 0, 0)
#define EXP2(x) __builtin_amdgcn_exp2f(x)
#define SWZ(row, off) ((off) ^ ((((row) ^ ((row) >> 3)) & 7) << 4))
#define SCL 0.18033688011112042f       // log2(e) / TEMP

#define KB_OFF 0u
#define QB_OFF (8u << 20)
#define VT_OFF (16u << 20)
#define ER_OFF (24u << 20)

__device__ __forceinline__ ushort f2bf(float x) {
    unsigned u = __float_as_uint(x);
    return (ushort)((u + 0x7FFFu + ((u >> 16) & 1u)) >> 16);
}

// ---------------------------------------------------------------------------
// Prepack: Q,K,Er -> bf16 row-major; V -> bf16 transposed [b][d][l]
// ---------------------------------------------------------------------------
__global__ __launch_bounds__(256) void pack_lin(
    const float* __restrict__ Q, const float* __restrict__ K,
    const float* __restrict__ Er, char* __restrict__ ws)
{
    const int NQ = B_ * L_ * D_ / 4;
    const int NE = L_ * D_ / 4;
    ushort4* Qb = (ushort4*)(ws + QB_OFF);
    ushort4* Kb = (ushort4*)(ws + KB_OFF);
    ushort4* Eb = (ushort4*)(ws + ER_OFF);
    for (int i = blockIdx.x * 256 + threadIdx.x; i < 2 * NQ + NE;
         i += gridDim.x * 256) {
        const f4* src; ushort4* dst; int j;
        if (i < NQ)          { src = (const f4*)Q;  dst = Qb; j = i; }
        else if (i < 2 * NQ) { src = (const f4*)K;  dst = Kb; j = i - NQ; }
        else                 { src = (const f4*)Er; dst = Eb; j = i - 2 * NQ; }
        f4 v = src[j];
        dst[j] = make_ushort4(f2bf(v.x), f2bf(v.y), f2bf(v.z), f2bf(v.w));
    }
}

__global__ __launch_bounds__(256) void pack_vt(
    const float* __restrict__ V, char* __restrict__ ws)
{
    __shared__ float sT[64][68];
    ushort* VT = (ushort*)(ws + VT_OFF);
    const int lt = blockIdx.x, b = blockIdx.y;
    const int l0 = lt * 64;
    const int r = threadIdx.x >> 4, c4 = threadIdx.x & 15;
#pragma unroll
    for (int i = 0; i < 4; ++i) {
        int row = r + 16 * i;
        f4 v = *(const f4*)(V + ((size_t)b * L_ + l0 + row) * D_ + 4 * c4);
        sT[row][4 * c4 + 0] = v.x; sT[row][4 * c4 + 1] = v.y;
        sT[row][4 * c4 + 2] = v.z; sT[row][4 * c4 + 3] = v.w;
    }
    __syncthreads();
    const int d = threadIdx.x >> 2, seg = threadIdx.x & 3;
    ushort tmp[16];
#pragma unroll
    for (int j = 0; j < 16; ++j) tmp[j] = f2bf(sT[seg * 16 + j][d]);
    ushort* dst = VT + ((size_t)b * D_ + d) * L_ + l0 + seg * 16;
#pragma unroll
    for (int j = 0; j < 4; ++j) *(ushort4*)(dst + 4 * j) = *(ushort4*)(tmp + 4 * j);
}

// ---------------------------------------------------------------------------
// Fused kernel v7:
//  - 40KB LDS (XOR-swizzled K/E/V staging, wave-private P buffer) -> 4 blk/CU
//  - skew shear fully in-register (shfl lane-rotation, kt-invariant src lanes)
//  - zeros of mirror strip written by this block (balances compute vs fill)
//  - XCD-aware (b,qt) swizzle: each XCD reuses 8 batches out of L2
// ---------------------------------------------------------------------------
__global__ __launch_bounds__(256, 4) void fused_v7(
    const char* __restrict__ ws, float* __restrict__ Pout, float* __restrict__ O)
{
    __shared__ __align__(16) char sK[64 * 128];    //  8192 B bf16 swz
    __shared__ __align__(16) char sE[128 * 128];   // 16384 B bf16 swz
    __shared__ __align__(16) char sV[64 * 128];    //  8192 B bf16 swz (V^T rows=d)
    __shared__ __align__(16) char sPb[4][2048];    //  8192 B wave-private P bf16

    const int tid = threadIdx.x;
    const int wgid = blockIdx.x;
    const int b  = (wgid & 7) | (((wgid >> 3) & 7) << 3);   // XCD shares 8 b's
    const int qt = 15 - (wgid >> 6);                        // heavy strips first
    const int q0 = qt * 64;
    const int lane = tid & 63, w = tid >> 6;
    const int fr = lane & 15, fc = lane >> 4;
    const int c4 = tid & 15, rsub = tid >> 4;
    const int t8 = tid >> 3, s8 = tid & 7;
    const int lb = (L_ - 64) - q0;

    const ushort* Kb = (const ushort*)(ws + KB_OFF) + (size_t)b * L_ * D_;
    const ushort* Qb = (const ushort*)(ws + QB_OFF) + (size_t)b * L_ * D_;
    const ushort* VT = (const ushort*)(ws + VT_OFF) + (size_t)b * D_ * L_;
    const ushort* Eb = (const ushort*)(ws + ER_OFF);

    char* pb = sPb[w];
    const int ebase = 48 - 16 * w;       // E LDS row base for this wave

    // Q fragments: wave's 16 rows, registers for the whole kernel
    bf16x8 qf[2];
#pragma unroll
    for (int kc = 0; kc < 2; ++kc)
        qf[kc] = *(const bf16x8*)(Qb + (q0 + 16 * w + fr) * D_ + kc * 32 + fc * 8);

    // hoisted shear constants (kt-invariant): src lane + register carry per r
    int srcl[4], carry[4];
#pragma unroll
    for (int r = 0; r < 4; ++r) {
        srcl[r]  = (lane & 48) | ((fr + 15 - 4 * fc - r) & 15);
        carry[r] = fr > 4 * fc + r;
    }

    // ---- staging helpers (coalesced 16B, reg round-trip, swizzled LDS) ----
    auto ldK = [&](int k0, int4* r) {
        r[0] = *(const int4*)(Kb + (size_t)k0 * D_ + tid * 8);
        r[1] = *(const int4*)(Kb + (size_t)k0 * D_ + 2048 + tid * 8);
    };
    auto wrK = [&](const int4* r) {
        *(int4*)(sK + t8 * 128 + ((s8 * 16) ^ ((t8 & 7) << 4)))          = r[0];
        *(int4*)(sK + (t8 + 32) * 128 + ((s8 * 16) ^ ((t8 & 7) << 4)))   = r[1];
    };
    auto ldE = [&](int k0, int4* r) {
#pragma unroll
        for (int j = 0; j < 4; ++j) {
            int l = lb + k0 + t8 + 32 * j;
            if (l > L_ - 1) l = L_ - 1;                   // clamp: masked only
            r[j] = *(const int4*)(Eb + (size_t)l * D_ + s8 * 8);
        }
    };
    auto wrE = [&](const int4* r) {
#pragma unroll
        for (int j = 0; j < 4; ++j)
            *(int4*)(sE + (t8 + 32 * j) * 128 + ((s8 * 16) ^ ((t8 & 7) << 4))) = r[j];
    };
    auto ldV = [&](int k0, int4* r) {
#pragma unroll
        for (int j = 0; j < 2; ++j)
            r[j] = *(const int4*)(VT + (size_t)(t8 + 32 * j) * L_ + k0 + s8 * 8);
    };
    auto wrV = [&](const int4* r) {
#pragma unroll
        for (int j = 0; j < 2; ++j)
            *(int4*)(sV + (t8 + 32 * j) * 128 + ((s8 * 16) ^ ((t8 & 7) << 4))) = r[j];
    };

    float sA[4] = {0.0f, 0.0f, 0.0f, 0.0f};
    int4 kreg[2], ereg[4], vreg[2];

    // ================= PHASE A: per-row sums of 2^(score*log2e) =============
    ldK(0, kreg); ldE(0, ereg);
    for (int kt = 0; kt <= qt; ++kt) {
        __syncthreads();                 // WAR on staging
        wrK(kreg); wrE(ereg);
        __syncthreads();

        f32x4 accC[4] = {};
        f32x4 accR[5] = {};
        {
            bf16x8 kf[4][2], ef[5][2];
#pragma unroll
            for (int a = 0; a < 4; ++a)
#pragma unroll
                for (int kc = 0; kc < 2; ++kc)
                    kf[a][kc] = *(const bf16x8*)(sK + (16 * a + fr) * 128 +
                                ((kc * 64 + fc * 16) ^ ((fr & 7) << 4)));
#pragma unroll
            for (int cc = 0; cc < 5; ++cc)
#pragma unroll
                for (int kc = 0; kc < 2; ++kc)
                    ef[cc][kc] = *(const bf16x8*)(sE + (ebase + 16 * cc + fr) * 128 +
                                ((kc * 64 + fc * 16) ^ ((fr & 7) << 4)));
            if (kt < qt) { ldK(64 * (kt + 1), kreg); ldE(64 * (kt + 1), ereg); }
#pragma unroll
            for (int a = 0; a < 4; ++a)
#pragma unroll
                for (int kc = 0; kc < 2; ++kc)
                    accC[a] = MFMA16(qf[kc], kf[a][kc], accC[a]);
#pragma unroll
            for (int cc = 0; cc < 5; ++cc)
#pragma unroll
                for (int kc = 0; kc < 2; ++kc)
                    accR[cc] = MFMA16(qf[kc], ef[cc][kc], accR[cc]);
        }
        const bool diag = (kt == qt);
#pragma unroll
        for (int r = 0; r < 4; ++r) {
            float g[5];
#pragma unroll
            for (int cc = 0; cc < 5; ++cc) g[cc] = __shfl(accR[cc][r], srcl[r], 64);
#pragma unroll
            for (int a = 0; a < 4; ++a) {
                float rel = carry[r] ? g[a + 1] : g[a];
                float v = (accC[a][r] + rel) * SCL;
                int kj = 16 * a + fr;
                if (!(diag && kj > 16 * w + 4 * fc + r)) sA[r] += EXP2(v);
            }
        }
    }
    // wave-local row-sum reduce over the 16 fr-lanes
    float inv[4];
#pragma unroll
    for (int r = 0; r < 4; ++r) {
        float s = sA[r];
#pragma unroll
        for (int off = 1; off <= 8; off <<= 1) s += __shfl_xor(s, off, 64);
        inv[r] = 1.0f / s;
    }

    // ================= PHASE B: probs + PV ==================================
    f32x4 accO[4] = {};
    ldK(0, kreg); ldE(0, ereg); ldV(0, vreg);
    for (int kt = 0; kt <= qt; ++kt) {
        const int k0 = 64 * kt;
        __syncthreads();
        wrK(kreg); wrE(ereg); wrV(vreg);
        __syncthreads();

        f32x4 accC[4] = {};
        f32x4 accR[5] = {};
        bf16x8 vf[4][2];
        {
            bf16x8 kf[4][2], ef[5][2];
#pragma unroll
            for (int a = 0; a < 4; ++a)
#pragma unroll
                for (int kc = 0; kc < 2; ++kc)
                    kf[a][kc] = *(const bf16x8*)(sK + (16 * a + fr) * 128 +
                                ((kc * 64 + fc * 16) ^ ((fr & 7) << 4)));
#pragma unroll
            for (int cc = 0; cc < 5; ++cc)
#pragma unroll
                for (int kc = 0; kc < 2; ++kc)
                    ef[cc][kc] = *(const bf16x8*)(sE + (ebase + 16 * cc + fr) * 128 +
                                ((kc * 64 + fc * 16) ^ ((fr & 7) << 4)));
#pragma unroll
            for (int dd = 0; dd < 4; ++dd)
#pragma unroll
                for (int kc = 0; kc < 2; ++kc)
                    vf[dd][kc] = *(const bf16x8*)(sV + (16 * dd + fr) * 128 +
                                ((kc * 64 + fc * 16) ^ ((fr & 7) << 4)));
            if (kt < qt) { ldK(k0 + 64, kreg); ldE(k0 + 64, ereg); ldV(k0 + 64, vreg); }
#pragma unroll
            for (int a = 0; a < 4; ++a)
#pragma unroll
                for (int kc = 0; kc < 2; ++kc)
                    accC[a] = MFMA16(qf[kc], kf[a][kc], accC[a]);
#pragma unroll
            for (int cc = 0; cc < 5; ++cc)
#pragma unroll
                for (int kc = 0; kc < 2; ++kc)
                    accR[cc] = MFMA16(qf[kc], ef[cc][kc], accR[cc]);
        }
        const bool diag = (kt == qt);
#pragma unroll
        for (int r = 0; r < 4; ++r) {
            float g[5];
#pragma unroll
            for (int cc = 0; cc < 5; ++cc) g[cc] = __shfl(accR[cc][r], srcl[r], 64);
#pragma unroll
            for (int a = 0; a < 4; ++a) {
                float rel = carry[r] ? g[a + 1] : g[a];
                float v = (accC[a][r] + rel) * SCL;
                int kj = 16 * a + fr;
                int qi = 4 * fc + r;
                float p = (diag && kj > 16 * w + qi) ? 0.0f : EXP2(v) * inv[r];
                Pout[((size_t)b * L_ + q0 + 16 * w + qi) * L_ + k0 + kj] = p;
                *(ushort*)(pb + qi * 128 + SWZ(qi, 2 * kj)) = f2bf(p);
            }
        }
        // PV: wave-private pa (in-wave lgkmcnt ordering, no barrier)
#pragma unroll
        for (int kc = 0; kc < 2; ++kc) {
            bf16x8 pa = *(const bf16x8*)(pb + fr * 128 + SWZ(fr, kc * 64 + fc * 16));
#pragma unroll
            for (int dd = 0; dd < 4; ++dd)
                accO[dd] = MFMA16(pa, vf[dd][kc], accO[dd]);
        }
    }

    // ---- zeros for the MIRROR strip's upper region (load-balanced fill) ----
    const int qtz = 15 - qt;                 // strip whose zeros we write
    const int nz4 = 16 * qt;                 // zero f4s per row in that strip
    const f4 z = {0.0f, 0.0f, 0.0f, 0.0f};
#pragma unroll
    for (int i = 0; i < 4; ++i) {
        int row = 64 * qtz + rsub + 16 * i;
        float* base = Pout + ((size_t)b * L_ + row) * L_ + 64 * (qtz + 1);
        for (int c = c4; c < nz4; c += 16) *(f4*)(base + 4 * c) = z;
    }
    // ---- O epilogue ----
#pragma unroll
    for (int dd = 0; dd < 4; ++dd)
#pragma unroll
        for (int r = 0; r < 4; ++r)
            O[((size_t)b * L_ + q0 + 16 * w + 4 * fc + r) * D_ + 16 * dd + fr] =
                accO[dd][r];
}

// ---------------------------------------------------------------------------
extern "C" void kernel_launch(void* const* d_in, const int* in_sizes, int n_in,
                              void* d_out, int out_size, void* d_ws, size_t ws_size,
                              hipStream_t stream)
{
    const float* Q  = (const float*)d_in[0];
    const float* K  = (const float*)d_in[1];
    const float* V  = (const float*)d_in[2];
    const float* Er = (const float*)d_in[3];

    float* Out  = (float*)d_out;                          // [B, L, D]
    float* Attn = (float*)d_out + (size_t)B_ * L_ * D_;   // [B, L, L] probs

    pack_lin<<<2048, 256, 0, stream>>>(Q, K, Er, (char*)d_ws);
    pack_vt<<<dim3(16, B_), 256, 0, stream>>>(V, (char*)d_ws);
    fused_v7<<<B_ * 16, 256, 0, stream>>>((const char*)d_ws, Attn, Out);
}

// Round 9
// 361.369 us; speedup vs baseline: 1.2188x; 1.2188x over previous
//
#include <hip/hip_runtime.h>
#include <math.h>

#define B_ 64
#define L_ 1024
#define D_ 64

typedef float4 f4;
typedef __attribute__((ext_vector_type(8))) short bf16x8;
typedef __attribute__((ext_vector_type(4))) float f32x4;

#define MFMA16(a, b, c) __builtin_amdgcn_mfma_f32_16x16x32_bf16(a, b, c, 0, 0, 0)
#define EXP2(x) __builtin_amdgcn_exp2f(x)
#define SWZ(row, off) ((off) ^ ((((row) ^ ((row) >> 3)) & 7) << 4))
#define SCL 0.18033688011112042f       // log2(e) / TEMP

#define KB_OFF 0u
#define QB_OFF (8u << 20)
#define VT_OFF (16u << 20)
#define ER_OFF (24u << 20)

__device__ __forceinline__ ushort f2bf(float x) {
    unsigned u = __float_as_uint(x);
    return (ushort)((u + 0x7FFFu + ((u >> 16) & 1u)) >> 16);
}
// NT store: ext_vector_type pointer (clang requires scalar/vector-of-scalar)
__device__ __forceinline__ void nt_store4(float* p, f32x4 v) {
    __builtin_nontemporal_store(v, (f32x4*)p);
}

// ---------------------------------------------------------------------------
// Prepack: Q,K,Er -> bf16 row-major; V -> bf16 transposed [b][d][l]
// ---------------------------------------------------------------------------
__global__ __launch_bounds__(256) void pack_lin(
    const float* __restrict__ Q, const float* __restrict__ K,
    const float* __restrict__ Er, char* __restrict__ ws)
{
    const int NQ = B_ * L_ * D_ / 4;
    const int NE = L_ * D_ / 4;
    ushort4* Qb = (ushort4*)(ws + QB_OFF);
    ushort4* Kb = (ushort4*)(ws + KB_OFF);
    ushort4* Eb = (ushort4*)(ws + ER_OFF);
    for (int i = blockIdx.x * 256 + threadIdx.x; i < 2 * NQ + NE;
         i += gridDim.x * 256) {
        const f4* src; ushort4* dst; int j;
        if (i < NQ)          { src = (const f4*)Q;  dst = Qb; j = i; }
        else if (i < 2 * NQ) { src = (const f4*)K;  dst = Kb; j = i - NQ; }
        else                 { src = (const f4*)Er; dst = Eb; j = i - 2 * NQ; }
        f4 v = src[j];
        dst[j] = make_ushort4(f2bf(v.x), f2bf(v.y), f2bf(v.z), f2bf(v.w));
    }
}

__global__ __launch_bounds__(256) void pack_vt(
    const float* __restrict__ V, char* __restrict__ ws)
{
    __shared__ float sT[64][68];
    ushort* VT = (ushort*)(ws + VT_OFF);
    const int lt = blockIdx.x, b = blockIdx.y;
    const int l0 = lt * 64;
    const int r = threadIdx.x >> 4, c4 = threadIdx.x & 15;
#pragma unroll
    for (int i = 0; i < 4; ++i) {
        int row = r + 16 * i;
        f4 v = *(const f4*)(V + ((size_t)b * L_ + l0 + row) * D_ + 4 * c4);
        sT[row][4 * c4 + 0] = v.x; sT[row][4 * c4 + 1] = v.y;
        sT[row][4 * c4 + 2] = v.z; sT[row][4 * c4 + 3] = v.w;
    }
    __syncthreads();
    const int d = threadIdx.x >> 2, seg = threadIdx.x & 3;
    ushort tmp[16];
#pragma unroll
    for (int j = 0; j < 16; ++j) tmp[j] = f2bf(sT[seg * 16 + j][d]);
    ushort* dst = VT + ((size_t)b * D_ + d) * L_ + l0 + seg * 16;
#pragma unroll
    for (int j = 0; j < 4; ++j) *(ushort4*)(dst + 4 * j) = *(ushort4*)(tmp + 4 * j);
}

// ---------------------------------------------------------------------------
// Fused kernel v8 = v7 structure + vectorized non-temporal P/O writes:
//  - P tile read back from wave-private LDS (bf16->f32) and stored as f4 NT
//    full-row segments: no partial-line RMW, no L2 write pollution
//  - zero-fill + O epilogue NT as well
// ---------------------------------------------------------------------------
__global__ __launch_bounds__(256, 4) void fused_v8(
    const char* __restrict__ ws, float* __restrict__ Pout, float* __restrict__ O)
{
    __shared__ __align__(16) char sK[64 * 128];    //  8192 B bf16 swz
    __shared__ __align__(16) char sE[128 * 128];   // 16384 B bf16 swz
    __shared__ __align__(16) char sV[64 * 128];    //  8192 B bf16 swz (V^T rows=d)
    __shared__ __align__(16) char sPb[4][2048];    //  8192 B wave-private P bf16

    const int tid = threadIdx.x;
    const int wgid = blockIdx.x;
    const int b  = wgid & 63;
    const int qt = 15 - (wgid >> 6);               // heavy strips first
    const int q0 = qt * 64;
    const int lane = tid & 63, w = tid >> 6;
    const int fr = lane & 15, fc = lane >> 4;
    const int c4 = tid & 15, rsub = tid >> 4;
    const int t8 = tid >> 3, s8 = tid & 7;
    const int lb = (L_ - 64) - q0;

    const ushort* Kb = (const ushort*)(ws + KB_OFF) + (size_t)b * L_ * D_;
    const ushort* Qb = (const ushort*)(ws + QB_OFF) + (size_t)b * L_ * D_;
    const ushort* VT = (const ushort*)(ws + VT_OFF) + (size_t)b * D_ * L_;
    const ushort* Eb = (const ushort*)(ws + ER_OFF);

    char* pb = sPb[w];
    const int ebase = 48 - 16 * w;                 // E LDS row base for this wave

    // readback lane mapping (P and O tiles): 4 lanes per row, 16B per lane
    const int oqi = lane >> 2, oc = lane & 3;
    const int osx = ((oqi ^ (oqi >> 3)) & 7) << 4;

    // Q fragments: wave's 16 rows, registers for the whole kernel
    bf16x8 qf[2];
#pragma unroll
    for (int kc = 0; kc < 2; ++kc)
        qf[kc] = *(const bf16x8*)(Qb + (q0 + 16 * w + fr) * D_ + kc * 32 + fc * 8);

    // hoisted shear constants (kt-invariant): src lane + register carry per r
    int srcl[4], carry[4];
#pragma unroll
    for (int r = 0; r < 4; ++r) {
        srcl[r]  = (lane & 48) | ((fr + 15 - 4 * fc - r) & 15);
        carry[r] = fr > 4 * fc + r;
    }

    // ---- staging helpers (coalesced 16B, reg round-trip, swizzled LDS) ----
    auto ldK = [&](int k0, int4* r) {
        r[0] = *(const int4*)(Kb + (size_t)k0 * D_ + tid * 8);
        r[1] = *(const int4*)(Kb + (size_t)k0 * D_ + 2048 + tid * 8);
    };
    auto wrK = [&](const int4* r) {
        *(int4*)(sK + t8 * 128 + ((s8 * 16) ^ ((t8 & 7) << 4)))        = r[0];
        *(int4*)(sK + (t8 + 32) * 128 + ((s8 * 16) ^ ((t8 & 7) << 4))) = r[1];
    };
    auto ldE = [&](int k0, int4* r) {
#pragma unroll
        for (int j = 0; j < 4; ++j) {
            int l = lb + k0 + t8 + 32 * j;
            if (l > L_ - 1) l = L_ - 1;            // clamp: masked entries only
            r[j] = *(const int4*)(Eb + (size_t)l * D_ + s8 * 8);
        }
    };
    auto wrE = [&](const int4* r) {
#pragma unroll
        for (int j = 0; j < 4; ++j)
            *(int4*)(sE + (t8 + 32 * j) * 128 + ((s8 * 16) ^ ((t8 & 7) << 4))) = r[j];
    };
    auto ldV = [&](int k0, int4* r) {
#pragma unroll
        for (int j = 0; j < 2; ++j)
            r[j] = *(const int4*)(VT + (size_t)(t8 + 32 * j) * L_ + k0 + s8 * 8);
    };
    auto wrV = [&](const int4* r) {
#pragma unroll
        for (int j = 0; j < 2; ++j)
            *(int4*)(sV + (t8 + 32 * j) * 128 + ((s8 * 16) ^ ((t8 & 7) << 4))) = r[j];
    };

    float sA[4] = {0.0f, 0.0f, 0.0f, 0.0f};
    int4 kreg[2], ereg[4], vreg[2];

    // ================= PHASE A: per-row sums of 2^(score*log2e) =============
    ldK(0, kreg); ldE(0, ereg);
    for (int kt = 0; kt <= qt; ++kt) {
        __syncthreads();                 // WAR on staging
        wrK(kreg); wrE(ereg);
        __syncthreads();

        f32x4 accC[4] = {};
        f32x4 accR[5] = {};
        {
            bf16x8 kf[4][2], ef[5][2];
#pragma unroll
            for (int a = 0; a < 4; ++a)
#pragma unroll
                for (int kc = 0; kc < 2; ++kc)
                    kf[a][kc] = *(const bf16x8*)(sK + (16 * a + fr) * 128 +
                                ((kc * 64 + fc * 16) ^ ((fr & 7) << 4)));
#pragma unroll
            for (int cc = 0; cc < 5; ++cc)
#pragma unroll
                for (int kc = 0; kc < 2; ++kc)
                    ef[cc][kc] = *(const bf16x8*)(sE + (ebase + 16 * cc + fr) * 128 +
                                ((kc * 64 + fc * 16) ^ ((fr & 7) << 4)));
            if (kt < qt) { ldK(64 * (kt + 1), kreg); ldE(64 * (kt + 1), ereg); }
#pragma unroll
            for (int a = 0; a < 4; ++a)
#pragma unroll
                for (int kc = 0; kc < 2; ++kc)
                    accC[a] = MFMA16(qf[kc], kf[a][kc], accC[a]);
#pragma unroll
            for (int cc = 0; cc < 5; ++cc)
#pragma unroll
                for (int kc = 0; kc < 2; ++kc)
                    accR[cc] = MFMA16(qf[kc], ef[cc][kc], accR[cc]);
        }
        const bool diag = (kt == qt);
#pragma unroll
        for (int r = 0; r < 4; ++r) {
            float g[5];
#pragma unroll
            for (int cc = 0; cc < 5; ++cc) g[cc] = __shfl(accR[cc][r], srcl[r], 64);
#pragma unroll
            for (int a = 0; a < 4; ++a) {
                float rel = carry[r] ? g[a + 1] : g[a];
                float v = (accC[a][r] + rel) * SCL;
                int kj = 16 * a + fr;
                if (!(diag && kj > 16 * w + 4 * fc + r)) sA[r] += EXP2(v);
            }
        }
    }
    // wave-local row-sum reduce over the 16 fr-lanes
    float inv[4];
#pragma unroll
    for (int r = 0; r < 4; ++r) {
        float s = sA[r];
#pragma unroll
        for (int off = 1; off <= 8; off <<= 1) s += __shfl_xor(s, off, 64);
        inv[r] = 1.0f / s;
    }

    // ================= PHASE B: probs + PV ==================================
    f32x4 accO[4] = {};
    ldK(0, kreg); ldE(0, ereg); ldV(0, vreg);
    for (int kt = 0; kt <= qt; ++kt) {
        const int k0 = 64 * kt;
        __syncthreads();
        wrK(kreg); wrE(ereg); wrV(vreg);
        __syncthreads();

        f32x4 accC[4] = {};
        f32x4 accR[5] = {};
        bf16x8 vf[4][2];
        {
            bf16x8 kf[4][2], ef[5][2];
#pragma unroll
            for (int a = 0; a < 4; ++a)
#pragma unroll
                for (int kc = 0; kc < 2; ++kc)
                    kf[a][kc] = *(const bf16x8*)(sK + (16 * a + fr) * 128 +
                                ((kc * 64 + fc * 16) ^ ((fr & 7) << 4)));
#pragma unroll
            for (int cc = 0; cc < 5; ++cc)
#pragma unroll
                for (int kc = 0; kc < 2; ++kc)
                    ef[cc][kc] = *(const bf16x8*)(sE + (ebase + 16 * cc + fr) * 128 +
                                ((kc * 64 + fc * 16) ^ ((fr & 7) << 4)));
#pragma unroll
            for (int dd = 0; dd < 4; ++dd)
#pragma unroll
                for (int kc = 0; kc < 2; ++kc)
                    vf[dd][kc] = *(const bf16x8*)(sV + (16 * dd + fr) * 128 +
                                ((kc * 64 + fc * 16) ^ ((fr & 7) << 4)));
            if (kt < qt) { ldK(k0 + 64, kreg); ldE(k0 + 64, ereg); ldV(k0 + 64, vreg); }
#pragma unroll
            for (int a = 0; a < 4; ++a)
#pragma unroll
                for (int kc = 0; kc < 2; ++kc)
                    accC[a] = MFMA16(qf[kc], kf[a][kc], accC[a]);
#pragma unroll
            for (int cc = 0; cc < 5; ++cc)
#pragma unroll
                for (int kc = 0; kc < 2; ++kc)
                    accR[cc] = MFMA16(qf[kc], ef[cc][kc], accR[cc]);
        }
        const bool diag = (kt == qt);
#pragma unroll
        for (int r = 0; r < 4; ++r) {
            float g[5];
#pragma unroll
            for (int cc = 0; cc < 5; ++cc) g[cc] = __shfl(accR[cc][r], srcl[r], 64);
#pragma unroll
            for (int a = 0; a < 4; ++a) {
                float rel = carry[r] ? g[a + 1] : g[a];
                float v = (accC[a][r] + rel) * SCL;
                int kj = 16 * a + fr;
                int qi = 4 * fc + r;
                float p = (diag && kj > 16 * w + qi) ? 0.0f : EXP2(v) * inv[r];
                *(ushort*)(pb + qi * 128 + SWZ(qi, 2 * kj)) = f2bf(p);
            }
        }
        // PV: wave-private pa (in-wave lgkmcnt ordering, no barrier)
#pragma unroll
        for (int kc = 0; kc < 2; ++kc) {
            bf16x8 pa = *(const bf16x8*)(pb + fr * 128 + SWZ(fr, kc * 64 + fc * 16));
#pragma unroll
            for (int dd = 0; dd < 4; ++dd)
                accO[dd] = MFMA16(pa, vf[dd][kc], accO[dd]);
        }
        // vectorized NT Pout writeback from pb (bf16 -> f32 via <<16)
        {
            float* prow = Pout + ((size_t)b * L_ + q0 + 16 * w + oqi) * L_ + k0;
#pragma unroll
            for (int j = 0; j < 4; ++j) {
                int o = (8 * oc + 32 * j) ^ osx;
                ushort4 u = *(const ushort4*)(pb + oqi * 128 + o);
                f32x4 f;
                f[0] = __uint_as_float((unsigned)(ushort)u.x << 16);
                f[1] = __uint_as_float((unsigned)(ushort)u.y << 16);
                f[2] = __uint_as_float((unsigned)(ushort)u.z << 16);
                f[3] = __uint_as_float((unsigned)(ushort)u.w << 16);
                nt_store4(prow + 4 * oc + 16 * j, f);
            }
        }
    }

    // ---- zeros for the MIRROR strip's upper region (load-balanced fill) ----
    const int qtz = 15 - qt;                 // strip whose zeros we write
    const int nz4 = 16 * qt;                 // zero f4s per row in that strip
    const f32x4 z = {0.0f, 0.0f, 0.0f, 0.0f};
#pragma unroll
    for (int i = 0; i < 4; ++i) {
        int row = 64 * qtz + rsub + 16 * i;
        float* base = Pout + ((size_t)b * L_ + row) * L_ + 64 * (qtz + 1);
        for (int c = c4; c < nz4; c += 16) nt_store4(base + 4 * c, z);
    }
    // ---- O epilogue: stage in pb, read back vectorized, NT store ----
#pragma unroll
    for (int dd = 0; dd < 4; ++dd)
#pragma unroll
        for (int r = 0; r < 4; ++r)
            *(ushort*)(pb + (4 * fc + r) * 128 + SWZ(4 * fc + r, 2 * (16 * dd + fr))) =
                f2bf(accO[dd][r]);
    {
        float* orow = O + ((size_t)b * L_ + q0 + 16 * w + oqi) * D_;
#pragma unroll
        for (int j = 0; j < 4; ++j) {
            int o = (8 * oc + 32 * j) ^ osx;
            ushort4 u = *(const ushort4*)(pb + oqi * 128 + o);
            f32x4 f;
            f[0] = __uint_as_float((unsigned)(ushort)u.x << 16);
            f[1] = __uint_as_float((unsigned)(ushort)u.y << 16);
            f[2] = __uint_as_float((unsigned)(ushort)u.z << 16);
            f[3] = __uint_as_float((unsigned)(ushort)u.w << 16);
            nt_store4(orow + 4 * oc + 16 * j, f);
        }
    }
}

// ---------------------------------------------------------------------------
extern "C" void kernel_launch(void* const* d_in, const int* in_sizes, int n_in,
                              void* d_out, int out_size, void* d_ws, size_t ws_size,
                              hipStream_t stream)
{
    const float* Q  = (const float*)d_in[0];
    const float* K  = (const float*)d_in[1];
    const float* V  = (const float*)d_in[2];
    const float* Er = (const float*)d_in[3];

    float* Out  = (float*)d_out;                          // [B, L, D]
    float* Attn = (float*)d_out + (size_t)B_ * L_ * D_;   // [B, L, L] probs

    pack_lin<<<2048, 256, 0, stream>>>(Q, K, Er, (char*)d_ws);
    pack_vt<<<dim3(16, B_), 256, 0, stream>>>(V, (char*)d_ws);
    fused_v8<<<B_ * 16, 256, 0, stream>>>((const char*)d_ws, Attn, Out);
}

// Round 10
// 260.460 us; speedup vs baseline: 1.6910x; 1.3874x over previous
//
#include <hip/hip_runtime.h>
#include <math.h>

#define B_ 64
#define L_ 1024
#define D_ 64
#define NQT 16

typedef float4 f4;
typedef __attribute__((ext_vector_type(8))) short bf16x8;
typedef __attribute__((ext_vector_type(4))) float f32x4;

#define MFMA16(a, b, c) __builtin_amdgcn_mfma_f32_16x16x32_bf16(a, b, c, 0, 0, 0)
#define EXP2(x) __builtin_amdgcn_exp2f(x)
#define SWZ(row, off) ((off) ^ ((((row) ^ ((row) >> 3)) & 7) << 4))
#define SCL 0.18033688011112042f       // log2(e) / TEMP

#define KB_OFF 0u
#define QB_OFF (8u << 20)
#define VT_OFF (16u << 20)
#define ER_OFF (24u << 20)

__device__ __forceinline__ ushort f2bf(float x) {
    unsigned u = __float_as_uint(x);
    return (ushort)((u + 0x7FFFu + ((u >> 16) & 1u)) >> 16);
}

// ---------------------------------------------------------------------------
// Prepack: Q,K,Er -> bf16 row-major; V -> bf16 transposed [b][d][l]
// ---------------------------------------------------------------------------
__global__ __launch_bounds__(256) void pack_lin(
    const float* __restrict__ Q, const float* __restrict__ K,
    const float* __restrict__ Er, char* __restrict__ ws)
{
    const int NQ = B_ * L_ * D_ / 4;
    const int NE = L_ * D_ / 4;
    ushort4* Qb = (ushort4*)(ws + QB_OFF);
    ushort4* Kb = (ushort4*)(ws + KB_OFF);
    ushort4* Eb = (ushort4*)(ws + ER_OFF);
    for (int i = blockIdx.x * 256 + threadIdx.x; i < 2 * NQ + NE;
         i += gridDim.x * 256) {
        const f4* src; ushort4* dst; int j;
        if (i < NQ)          { src = (const f4*)Q;  dst = Qb; j = i; }
        else if (i < 2 * NQ) { src = (const f4*)K;  dst = Kb; j = i - NQ; }
        else                 { src = (const f4*)Er; dst = Eb; j = i - 2 * NQ; }
        f4 v = src[j];
        dst[j] = make_ushort4(f2bf(v.x), f2bf(v.y), f2bf(v.z), f2bf(v.w));
    }
}

__global__ __launch_bounds__(256) void pack_vt(
    const float* __restrict__ V, char* __restrict__ ws)
{
    __shared__ float sT[64][68];
    ushort* VT = (ushort*)(ws + VT_OFF);
    const int lt = blockIdx.x, b = blockIdx.y;
    const int l0 = lt * 64;
    const int r = threadIdx.x >> 4, c4 = threadIdx.x & 15;
#pragma unroll
    for (int i = 0; i < 4; ++i) {
        int row = r + 16 * i;
        f4 v = *(const f4*)(V + ((size_t)b * L_ + l0 + row) * D_ + 4 * c4);
        sT[row][4 * c4 + 0] = v.x; sT[row][4 * c4 + 1] = v.y;
        sT[row][4 * c4 + 2] = v.z; sT[row][4 * c4 + 3] = v.w;
    }
    __syncthreads();
    const int d = threadIdx.x >> 2, seg = threadIdx.x & 3;
    ushort tmp[16];
#pragma unroll
    for (int j = 0; j < 16; ++j) tmp[j] = f2bf(sT[seg * 16 + j][d]);
    ushort* dst = VT + ((size_t)b * D_ + d) * L_ + l0 + seg * 16;
#pragma unroll
    for (int j = 0; j < 4; ++j) *(ushort4*)(dst + 4 * j) = *(ushort4*)(tmp + 4 * j);
}

// ---------------------------------------------------------------------------
// Fused kernel v9 = v6 (proven memory behavior) + in-register shear (shfl):
//  - wave owns 16 q-rows x 64 k-cols; stats, P staging wave-private
//  - padded-72 LDS staging, plain scalar P stores (64B-line pattern)
//  - no sSh: LDS 44KB -> 3 blocks/CU
// ---------------------------------------------------------------------------
__global__ __launch_bounds__(256, 3) void fused_v9(
    const char* __restrict__ ws, float* __restrict__ Pout, float* __restrict__ O)
{
    __shared__ __align__(16) ushort sK[64 * 72];          //  9216 B
    __shared__ __align__(16) ushort sE[128 * 72];         // 18432 B
    __shared__ __align__(16) ushort sV[64 * 72];          //  9216 B
    __shared__ __align__(16) char   sPb[4][2048];         //  8192 B wave-private

    const int tid = threadIdx.x;
    const int b = blockIdx.x;
    const int qt = 15 - (int)blockIdx.y;                  // heavy strips first
    const int q0 = qt * 64;
    const int lane = tid & 63, w = tid >> 6;
    const int fr = lane & 15, fc = lane >> 4;
    const int c4 = tid & 15, rsub = tid >> 4;
    const int t8 = tid >> 3, s8 = tid & 7;
    const int lb = (L_ - 64) - q0;

    const ushort* Kb = (const ushort*)(ws + KB_OFF) + (size_t)b * L_ * D_;
    const ushort* Qb = (const ushort*)(ws + QB_OFF) + (size_t)b * L_ * D_;
    const ushort* VT = (const ushort*)(ws + VT_OFF) + (size_t)b * D_ * L_;
    const ushort* Eb = (const ushort*)(ws + ER_OFF);

    char* pb = sPb[w];
    const int ebase = 48 - 16 * w;       // E LDS row base for this wave

    // Q fragments: wave's 16 rows, in registers for the whole kernel
    bf16x8 qf[2];
#pragma unroll
    for (int kc = 0; kc < 2; ++kc)
        qf[kc] = *(const bf16x8*)(Qb + (q0 + 16 * w + fr) * D_ + kc * 32 + fc * 8);

    // hoisted shear constants (kt-invariant): src lane + register carry per r
    int srcl[4], carry[4];
#pragma unroll
    for (int r = 0; r < 4; ++r) {
        srcl[r]  = (lane & 48) | ((fr + 15 - 4 * fc - r) & 15);
        carry[r] = fr > 4 * fc + r;
    }

    auto ldK = [&](int k0, int4* r) {
        r[0] = *(const int4*)(Kb + (size_t)k0 * D_ + tid * 8);
        r[1] = *(const int4*)(Kb + (size_t)k0 * D_ + 2048 + tid * 8);
    };
    auto wrK = [&](const int4* r) {
        *(int4*)(sK + t8 * 72 + s8 * 8)        = r[0];
        *(int4*)(sK + (t8 + 32) * 72 + s8 * 8) = r[1];
    };
    auto ldE = [&](int k0, int4* r) {
#pragma unroll
        for (int j = 0; j < 4; ++j) {
            int l = lb + k0 + t8 + 32 * j;
            if (l > L_ - 1) l = L_ - 1;                   // clamp: masked only
            r[j] = *(const int4*)(Eb + (size_t)l * D_ + s8 * 8);
        }
    };
    auto wrE = [&](const int4* r) {
#pragma unroll
        for (int j = 0; j < 4; ++j)
            *(int4*)(sE + (t8 + 32 * j) * 72 + s8 * 8) = r[j];
    };
    auto ldV = [&](int k0, int4* r) {
#pragma unroll
        for (int j = 0; j < 2; ++j)
            r[j] = *(const int4*)(VT + (size_t)(t8 + 32 * j) * L_ + k0 + s8 * 8);
    };
    auto wrV = [&](const int4* r) {
#pragma unroll
        for (int j = 0; j < 2; ++j)
            *(int4*)(sV + (t8 + 32 * j) * 72 + s8 * 8) = r[j];
    };

    float sA[4] = {0.0f, 0.0f, 0.0f, 0.0f};
    int4 kreg[2], ereg[4], vreg[2];

    // ================= PHASE A: per-row sums of 2^(score*log2e) =============
    ldK(0, kreg); ldE(0, ereg);
    for (int kt = 0; kt <= qt; ++kt) {
        __syncthreads();                 // WAR on staging
        wrK(kreg); wrE(ereg);
        __syncthreads();                 // staging visible

        f32x4 accC[4] = {};
        f32x4 accR[5] = {};
        {
            bf16x8 kf[4][2], ef[5][2];
#pragma unroll
            for (int a = 0; a < 4; ++a)
#pragma unroll
                for (int kc = 0; kc < 2; ++kc)
                    kf[a][kc] = *(const bf16x8*)(sK + (16 * a + fr) * 72 + kc * 32 + fc * 8);
#pragma unroll
            for (int cc = 0; cc < 5; ++cc)
#pragma unroll
                for (int kc = 0; kc < 2; ++kc)
                    ef[cc][kc] = *(const bf16x8*)(sE + (ebase + 16 * cc + fr) * 72 + kc * 32 + fc * 8);
            if (kt < qt) { ldK(64 * (kt + 1), kreg); ldE(64 * (kt + 1), ereg); }
#pragma unroll
            for (int a = 0; a < 4; ++a)
#pragma unroll
                for (int kc = 0; kc < 2; ++kc)
                    accC[a] = MFMA16(qf[kc], kf[a][kc], accC[a]);
#pragma unroll
            for (int cc = 0; cc < 5; ++cc)
#pragma unroll
                for (int kc = 0; kc < 2; ++kc)
                    accR[cc] = MFMA16(qf[kc], ef[cc][kc], accR[cc]);
        }
        const bool diag = (kt == qt);
#pragma unroll
        for (int r = 0; r < 4; ++r) {
            float g[5];
#pragma unroll
            for (int cc = 0; cc < 5; ++cc) g[cc] = __shfl(accR[cc][r], srcl[r], 64);
#pragma unroll
            for (int a = 0; a < 4; ++a) {
                float rel = carry[r] ? g[a + 1] : g[a];
                float v = (accC[a][r] + rel) * SCL;
                int kj = 16 * a + fr;
                if (!(diag && kj > 16 * w + 4 * fc + r)) sA[r] += EXP2(v);
            }
        }
    }
    // wave-local row-sum reduce over the 16 fr-lanes
    float inv[4];
#pragma unroll
    for (int r = 0; r < 4; ++r) {
        float s = sA[r];
#pragma unroll
        for (int off = 1; off <= 8; off <<= 1) s += __shfl_xor(s, off, 64);
        inv[r] = 1.0f / s;
    }

    // ================= PHASE B: probs + PV ==================================
    f32x4 accO[4] = {};
    ldK(0, kreg); ldE(0, ereg); ldV(0, vreg);
    for (int kt = 0; kt <= qt; ++kt) {
        const int k0 = 64 * kt;
        __syncthreads();
        wrK(kreg); wrE(ereg); wrV(vreg);
        __syncthreads();

        f32x4 accC[4] = {};
        f32x4 accR[5] = {};
        bf16x8 vf[4][2];
        {
            bf16x8 kf[4][2], ef[5][2];
#pragma unroll
            for (int a = 0; a < 4; ++a)
#pragma unroll
                for (int kc = 0; kc < 2; ++kc)
                    kf[a][kc] = *(const bf16x8*)(sK + (16 * a + fr) * 72 + kc * 32 + fc * 8);
#pragma unroll
            for (int cc = 0; cc < 5; ++cc)
#pragma unroll
                for (int kc = 0; kc < 2; ++kc)
                    ef[cc][kc] = *(const bf16x8*)(sE + (ebase + 16 * cc + fr) * 72 + kc * 32 + fc * 8);
#pragma unroll
            for (int dd = 0; dd < 4; ++dd)
#pragma unroll
                for (int kc = 0; kc < 2; ++kc)
                    vf[dd][kc] = *(const bf16x8*)(sV + (16 * dd + fr) * 72 + kc * 32 + fc * 8);
            if (kt < qt) { ldK(k0 + 64, kreg); ldE(k0 + 64, ereg); ldV(k0 + 64, vreg); }
#pragma unroll
            for (int a = 0; a < 4; ++a)
#pragma unroll
                for (int kc = 0; kc < 2; ++kc)
                    accC[a] = MFMA16(qf[kc], kf[a][kc], accC[a]);
#pragma unroll
            for (int cc = 0; cc < 5; ++cc)
#pragma unroll
                for (int kc = 0; kc < 2; ++kc)
                    accR[cc] = MFMA16(qf[kc], ef[cc][kc], accR[cc]);
        }
        const bool diag = (kt == qt);
#pragma unroll
        for (int r = 0; r < 4; ++r) {
            float g[5];
#pragma unroll
            for (int cc = 0; cc < 5; ++cc) g[cc] = __shfl(accR[cc][r], srcl[r], 64);
#pragma unroll
            for (int a = 0; a < 4; ++a) {
                float rel = carry[r] ? g[a + 1] : g[a];
                float v = (accC[a][r] + rel) * SCL;
                int kj = 16 * a + fr;
                int qi = 4 * fc + r;
                float p = (diag && kj > 16 * w + qi) ? 0.0f : EXP2(v) * inv[r];
                Pout[((size_t)b * L_ + q0 + 16 * w + qi) * L_ + k0 + kj] = p;
                *(ushort*)(pb + qi * 128 + SWZ(qi, 2 * kj)) = f2bf(p);
            }
        }
        // PV: wave-private pa (in-wave lgkmcnt ordering, no barrier)
#pragma unroll
        for (int kc = 0; kc < 2; ++kc) {
            bf16x8 pa = *(const bf16x8*)(pb + fr * 128 + SWZ(fr, kc * 64 + fc * 16));
#pragma unroll
            for (int dd = 0; dd < 4; ++dd)
                accO[dd] = MFMA16(pa, vf[dd][kc], accO[dd]);
        }
    }

    // ---- zeros for this strip's untouched upper region ----
    const int nz4 = 16 * (15 - qt);
    const f4 z = {0.0f, 0.0f, 0.0f, 0.0f};
#pragma unroll
    for (int i = 0; i < 4; ++i) {
        int row = rsub + 16 * i;
        float* base = Pout + ((size_t)b * L_ + q0 + row) * L_ + 64 * (qt + 1);
        for (int c = c4; c < nz4; c += 16) *(f4*)(base + 4 * c) = z;
    }
    // ---- O epilogue ----
#pragma unroll
    for (int dd = 0; dd < 4; ++dd)
#pragma unroll
        for (int r = 0; r < 4; ++r)
            O[((size_t)b * L_ + q0 + 16 * w + 4 * fc + r) * D_ + 16 * dd + fr] =
                accO[dd][r];
}

// ---------------------------------------------------------------------------
extern "C" void kernel_launch(void* const* d_in, const int* in_sizes, int n_in,
                              void* d_out, int out_size, void* d_ws, size_t ws_size,
                              hipStream_t stream)
{
    const float* Q  = (const float*)d_in[0];
    const float* K  = (const float*)d_in[1];
    const float* V  = (const float*)d_in[2];
    const float* Er = (const float*)d_in[3];

    float* Out  = (float*)d_out;                          // [B, L, D]
    float* Attn = (float*)d_out + (size_t)B_ * L_ * D_;   // [B, L, L] probs

    pack_lin<<<2048, 256, 0, stream>>>(Q, K, Er, (char*)d_ws);
    pack_vt<<<dim3(16, B_), 256, 0, stream>>>(V, (char*)d_ws);
    fused_v9<<<dim3(B_, NQT), 256, 0, stream>>>((const char*)d_ws, Attn, Out);
}

// Round 11
// 166.721 us; speedup vs baseline: 2.6417x; 1.5623x over previous
//
#include <hip/hip_runtime.h>
#include <math.h>

#define B_ 64
#define L_ 1024
#define D_ 64
#define NQT 16

typedef float4 f4;
typedef __attribute__((ext_vector_type(8))) short bf16x8;
typedef __attribute__((ext_vector_type(4))) float f32x4;

#define MFMA16(a, b, c) __builtin_amdgcn_mfma_f32_16x16x32_bf16(a, b, c, 0, 0, 0)
#define EXP2(x) __builtin_amdgcn_exp2f(x)
#define SWZ(row, off) ((off) ^ ((((row) ^ ((row) >> 3)) & 7) << 4))
#define SCL 0.18033688011112042f       // log2(e) / TEMP

#define KB_OFF 0u
#define QB_OFF (8u << 20)
#define VT_OFF (16u << 20)
#define ER_OFF (24u << 20)

__device__ __forceinline__ ushort f2bf(float x) {
    unsigned u = __float_as_uint(x);
    return (ushort)((u + 0x7FFFu + ((u >> 16) & 1u)) >> 16);
}

// ---------------------------------------------------------------------------
// Prepack: Q,K,Er -> bf16 row-major; V -> bf16 transposed [b][d][l]
// ---------------------------------------------------------------------------
__global__ __launch_bounds__(256) void pack_lin(
    const float* __restrict__ Q, const float* __restrict__ K,
    const float* __restrict__ Er, char* __restrict__ ws)
{
    const int NQ = B_ * L_ * D_ / 4;
    const int NE = L_ * D_ / 4;
    ushort4* Qb = (ushort4*)(ws + QB_OFF);
    ushort4* Kb = (ushort4*)(ws + KB_OFF);
    ushort4* Eb = (ushort4*)(ws + ER_OFF);
    for (int i = blockIdx.x * 256 + threadIdx.x; i < 2 * NQ + NE;
         i += gridDim.x * 256) {
        const f4* src; ushort4* dst; int j;
        if (i < NQ)          { src = (const f4*)Q;  dst = Qb; j = i; }
        else if (i < 2 * NQ) { src = (const f4*)K;  dst = Kb; j = i - NQ; }
        else                 { src = (const f4*)Er; dst = Eb; j = i - 2 * NQ; }
        f4 v = src[j];
        dst[j] = make_ushort4(f2bf(v.x), f2bf(v.y), f2bf(v.z), f2bf(v.w));
    }
}

__global__ __launch_bounds__(256) void pack_vt(
    const float* __restrict__ V, char* __restrict__ ws)
{
    __shared__ float sT[64][68];
    ushort* VT = (ushort*)(ws + VT_OFF);
    const int lt = blockIdx.x, b = blockIdx.y;
    const int l0 = lt * 64;
    const int r = threadIdx.x >> 4, c4 = threadIdx.x & 15;
#pragma unroll
    for (int i = 0; i < 4; ++i) {
        int row = r + 16 * i;
        f4 v = *(const f4*)(V + ((size_t)b * L_ + l0 + row) * D_ + 4 * c4);
        sT[row][4 * c4 + 0] = v.x; sT[row][4 * c4 + 1] = v.y;
        sT[row][4 * c4 + 2] = v.z; sT[row][4 * c4 + 3] = v.w;
    }
    __syncthreads();
    const int d = threadIdx.x >> 2, seg = threadIdx.x & 3;
    ushort tmp[16];
#pragma unroll
    for (int j = 0; j < 16; ++j) tmp[j] = f2bf(sT[seg * 16 + j][d]);
    ushort* dst = VT + ((size_t)b * D_ + d) * L_ + l0 + seg * 16;
#pragma unroll
    for (int j = 0; j < 4; ++j) *(ushort4*)(dst + 4 * j) = *(ushort4*)(tmp + 4 * j);
}

// ---------------------------------------------------------------------------
// Fused kernel v10 = v6's 2-blk/CU memory regime + in-register shear +
// DOUBLE-BUFFERED swizzled staging -> ONE barrier per tile-iteration.
//  - wave owns 16 q-rows x 64 k-cols; stats/P staging wave-private
//  - 72KB LDS total; __launch_bounds__(256,2) pins the proven occupancy
// ---------------------------------------------------------------------------
__global__ __launch_bounds__(256, 2) void fused_v10(
    const char* __restrict__ ws, float* __restrict__ Pout, float* __restrict__ O)
{
    __shared__ __align__(16) char sK[2][64 * 128];    // 16384 B
    __shared__ __align__(16) char sE[2][128 * 128];   // 32768 B
    __shared__ __align__(16) char sV[2][64 * 128];    // 16384 B
    __shared__ __align__(16) char sPb[4][2048];       //  8192 B wave-private

    const int tid = threadIdx.x;
    const int b = blockIdx.x;
    const int qt = 15 - (int)blockIdx.y;              // heavy strips first
    const int q0 = qt * 64;
    const int lane = tid & 63, w = tid >> 6;
    const int fr = lane & 15, fc = lane >> 4;
    const int c4 = tid & 15, rsub = tid >> 4;
    const int t8 = tid >> 3, s8 = tid & 7;
    const int lb = (L_ - 64) - q0;

    const ushort* Kb = (const ushort*)(ws + KB_OFF) + (size_t)b * L_ * D_;
    const ushort* Qb = (const ushort*)(ws + QB_OFF) + (size_t)b * L_ * D_;
    const ushort* VT = (const ushort*)(ws + VT_OFF) + (size_t)b * D_ * L_;
    const ushort* Eb = (const ushort*)(ws + ER_OFF);

    char* pb = sPb[w];
    const int ebase = 48 - 16 * w;        // E row base for this wave's frags
    const int so = (s8 * 16) ^ ((t8 & 7) << 4);   // staging write swizzle
    const int rx = (fr & 7) << 4;                 // frag read swizzle

    // Q fragments: wave's 16 rows, in registers for the whole kernel
    bf16x8 qf[2];
#pragma unroll
    for (int kc = 0; kc < 2; ++kc)
        qf[kc] = *(const bf16x8*)(Qb + (q0 + 16 * w + fr) * D_ + kc * 32 + fc * 8);

    // hoisted shear constants (kt-invariant): src lane + register carry per r
    int srcl[4], carry[4];
#pragma unroll
    for (int r = 0; r < 4; ++r) {
        srcl[r]  = (lane & 48) | ((fr + 15 - 4 * fc - r) & 15);
        carry[r] = fr > 4 * fc + r;
    }

    auto ldK = [&](int k0, int4* r) {
        r[0] = *(const int4*)(Kb + (size_t)k0 * D_ + tid * 8);
        r[1] = *(const int4*)(Kb + (size_t)k0 * D_ + 2048 + tid * 8);
    };
    auto wrK = [&](int buf, const int4* r) {
        *(int4*)(sK[buf] + t8 * 128 + so)        = r[0];
        *(int4*)(sK[buf] + (t8 + 32) * 128 + so) = r[1];
    };
    auto ldE = [&](int k0, int4* r) {
#pragma unroll
        for (int j = 0; j < 4; ++j) {
            int l = lb + k0 + t8 + 32 * j;
            if (l > L_ - 1) l = L_ - 1;           // clamp: masked entries only
            r[j] = *(const int4*)(Eb + (size_t)l * D_ + s8 * 8);
        }
    };
    auto wrE = [&](int buf, const int4* r) {
#pragma unroll
        for (int j = 0; j < 4; ++j)
            *(int4*)(sE[buf] + (t8 + 32 * j) * 128 + so) = r[j];
    };
    auto ldV = [&](int k0, int4* r) {
#pragma unroll
        for (int j = 0; j < 2; ++j)
            r[j] = *(const int4*)(VT + (size_t)(t8 + 32 * j) * L_ + k0 + s8 * 8);
    };
    auto wrV = [&](int buf, const int4* r) {
#pragma unroll
        for (int j = 0; j < 2; ++j)
            *(int4*)(sV[buf] + (t8 + 32 * j) * 128 + so) = r[j];
    };

    float sA[4] = {0.0f, 0.0f, 0.0f, 0.0f};
    int4 kreg[2], ereg[4], vreg[2];

    // ================= PHASE A: per-row sums of 2^(score*log2e) =============
    ldK(0, kreg); ldE(0, ereg);
    for (int kt = 0; kt <= qt; ++kt) {
        const int cur = kt & 1;
        wrK(cur, kreg); wrE(cur, ereg);   // ds_write waits on its own vmcnt
        __syncthreads();                  // single barrier per iteration
        if (kt < qt) { ldK(64 * (kt + 1), kreg); ldE(64 * (kt + 1), ereg); }

        f32x4 accC[4] = {};
        f32x4 accR[5] = {};
        {
            bf16x8 kf[4][2], ef[5][2];
#pragma unroll
            for (int a = 0; a < 4; ++a)
#pragma unroll
                for (int kc = 0; kc < 2; ++kc)
                    kf[a][kc] = *(const bf16x8*)(sK[cur] + (16 * a + fr) * 128 +
                                                 ((kc * 64 + fc * 16) ^ rx));
#pragma unroll
            for (int cc = 0; cc < 5; ++cc)
#pragma unroll
                for (int kc = 0; kc < 2; ++kc)
                    ef[cc][kc] = *(const bf16x8*)(sE[cur] + (ebase + 16 * cc + fr) * 128 +
                                                  ((kc * 64 + fc * 16) ^ rx));
#pragma unroll
            for (int a = 0; a < 4; ++a)
#pragma unroll
                for (int kc = 0; kc < 2; ++kc)
                    accC[a] = MFMA16(qf[kc], kf[a][kc], accC[a]);
#pragma unroll
            for (int cc = 0; cc < 5; ++cc)
#pragma unroll
                for (int kc = 0; kc < 2; ++kc)
                    accR[cc] = MFMA16(qf[kc], ef[cc][kc], accR[cc]);
        }
        const bool diag = (kt == qt);
#pragma unroll
        for (int r = 0; r < 4; ++r) {
            float g[5];
#pragma unroll
            for (int cc = 0; cc < 5; ++cc) g[cc] = __shfl(accR[cc][r], srcl[r], 64);
#pragma unroll
            for (int a = 0; a < 4; ++a) {
                float rel = carry[r] ? g[a + 1] : g[a];
                float v = (accC[a][r] + rel) * SCL;
                int kj = 16 * a + fr;
                if (!(diag && kj > 16 * w + 4 * fc + r)) sA[r] += EXP2(v);
            }
        }
    }
    // wave-local row-sum reduce over the 16 fr-lanes
    float inv[4];
#pragma unroll
    for (int r = 0; r < 4; ++r) {
        float s = sA[r];
#pragma unroll
        for (int off = 1; off <= 8; off <<= 1) s += __shfl_xor(s, off, 64);
        inv[r] = 1.0f / s;
    }

    __syncthreads();    // all phase-A frag reads done before buffers reused

    // ================= PHASE B: probs + PV ==================================
    f32x4 accO[4] = {};
    ldK(0, kreg); ldE(0, ereg); ldV(0, vreg);
    for (int kt = 0; kt <= qt; ++kt) {
        const int k0 = 64 * kt;
        const int cur = kt & 1;
        wrK(cur, kreg); wrE(cur, ereg); wrV(cur, vreg);
        __syncthreads();
        if (kt < qt) { ldK(k0 + 64, kreg); ldE(k0 + 64, ereg); ldV(k0 + 64, vreg); }

        f32x4 accC[4] = {};
        f32x4 accR[5] = {};
        bf16x8 vf[4][2];
        {
            bf16x8 kf[4][2], ef[5][2];
#pragma unroll
            for (int a = 0; a < 4; ++a)
#pragma unroll
                for (int kc = 0; kc < 2; ++kc)
                    kf[a][kc] = *(const bf16x8*)(sK[cur] + (16 * a + fr) * 128 +
                                                 ((kc * 64 + fc * 16) ^ rx));
#pragma unroll
            for (int cc = 0; cc < 5; ++cc)
#pragma unroll
                for (int kc = 0; kc < 2; ++kc)
                    ef[cc][kc] = *(const bf16x8*)(sE[cur] + (ebase + 16 * cc + fr) * 128 +
                                                  ((kc * 64 + fc * 16) ^ rx));
#pragma unroll
            for (int dd = 0; dd < 4; ++dd)
#pragma unroll
                for (int kc = 0; kc < 2; ++kc)
                    vf[dd][kc] = *(const bf16x8*)(sV[cur] + (16 * dd + fr) * 128 +
                                                  ((kc * 64 + fc * 16) ^ rx));
#pragma unroll
            for (int a = 0; a < 4; ++a)
#pragma unroll
                for (int kc = 0; kc < 2; ++kc)
                    accC[a] = MFMA16(qf[kc], kf[a][kc], accC[a]);
#pragma unroll
            for (int cc = 0; cc < 5; ++cc)
#pragma unroll
                for (int kc = 0; kc < 2; ++kc)
                    accR[cc] = MFMA16(qf[kc], ef[cc][kc], accR[cc]);
        }
        const bool diag = (kt == qt);
#pragma unroll
        for (int r = 0; r < 4; ++r) {
            float g[5];
#pragma unroll
            for (int cc = 0; cc < 5; ++cc) g[cc] = __shfl(accR[cc][r], srcl[r], 64);
#pragma unroll
            for (int a = 0; a < 4; ++a) {
                float rel = carry[r] ? g[a + 1] : g[a];
                float v = (accC[a][r] + rel) * SCL;
                int kj = 16 * a + fr;
                int qi = 4 * fc + r;
                float p = (diag && kj > 16 * w + qi) ? 0.0f : EXP2(v) * inv[r];
                Pout[((size_t)b * L_ + q0 + 16 * w + qi) * L_ + k0 + kj] = p;
                *(ushort*)(pb + qi * 128 + SWZ(qi, 2 * kj)) = f2bf(p);
            }
        }
        // PV: wave-private pa (in-wave lgkmcnt ordering, no barrier)
#pragma unroll
        for (int kc = 0; kc < 2; ++kc) {
            bf16x8 pa = *(const bf16x8*)(pb + fr * 128 + SWZ(fr, kc * 64 + fc * 16));
#pragma unroll
            for (int dd = 0; dd < 4; ++dd)
                accO[dd] = MFMA16(pa, vf[dd][kc], accO[dd]);
        }
    }

    // ---- zeros for this strip's untouched upper region ----
    const int nz4 = 16 * (15 - qt);
    const f4 z = {0.0f, 0.0f, 0.0f, 0.0f};
#pragma unroll
    for (int i = 0; i < 4; ++i) {
        int row = rsub + 16 * i;
        float* base = Pout + ((size_t)b * L_ + q0 + row) * L_ + 64 * (qt + 1);
        for (int c = c4; c < nz4; c += 16) *(f4*)(base + 4 * c) = z;
    }
    // ---- O epilogue ----
#pragma unroll
    for (int dd = 0; dd < 4; ++dd)
#pragma unroll
        for (int r = 0; r < 4; ++r)
            O[((size_t)b * L_ + q0 + 16 * w + 4 * fc + r) * D_ + 16 * dd + fr] =
                accO[dd][r];
}

// ---------------------------------------------------------------------------
extern "C" void kernel_launch(void* const* d_in, const int* in_sizes, int n_in,
                              void* d_out, int out_size, void* d_ws, size_t ws_size,
                              hipStream_t stream)
{
    const float* Q  = (const float*)d_in[0];
    const float* K  = (const float*)d_in[1];
    const float* V  = (const float*)d_in[2];
    const float* Er = (const float*)d_in[3];

    float* Out  = (float*)d_out;                          // [B, L, D]
    float* Attn = (float*)d_out + (size_t)B_ * L_ * D_;   // [B, L, L] probs

    pack_lin<<<2048, 256, 0, stream>>>(Q, K, Er, (char*)d_ws);
    pack_vt<<<dim3(16, B_), 256, 0, stream>>>(V, (char*)d_ws);
    fused_v10<<<dim3(B_, NQT), 256, 0, stream>>>((const char*)d_ws, Attn, Out);
}